// Round 7
// baseline (264.682 us; speedup 1.0000x reference)
//
#include <hip/hip_runtime.h>

#define NN 50000
#define NE 800000
#define IND 32
#define DD 16
#define BB 8
#define NC 128   // BB*DD
#define EPSBN 1e-5f
#define SCB ((NN + 255) / 256)   // 196 scan blocks
#define G 128                    // histogram blocks per direction
#define CHE (NE / G)             // 6250 edges per hist block
#define WPN (NN / 4)             // 12500 packed words (4 uint8 counters each)
#define GNB 125                  // nodes per gemm1 block (400 blocks exact)
#define NGB 3125                 // gather blocks (16 nodes each, exact)

typedef unsigned int uint;
typedef unsigned short ushort;

__device__ __forceinline__ ushort f2bf(float f) {
  uint u = __float_as_uint(f);
  return (ushort)((u + 0x7fffu + ((u >> 16) & 1u)) >> 16);  // RNE
}
__device__ __forceinline__ uint pack2bf(float lo, float hi) {
  return (uint)f2bf(lo) | ((uint)f2bf(hi) << 16);
}
__device__ __forceinline__ void add8(float* acc, uint4 v) {
  acc[0] += __uint_as_float(v.x << 16);
  acc[1] += __uint_as_float(v.x & 0xffff0000u);
  acc[2] += __uint_as_float(v.y << 16);
  acc[3] += __uint_as_float(v.y & 0xffff0000u);
  acc[4] += __uint_as_float(v.z << 16);
  acc[5] += __uint_as_float(v.z & 0xffff0000u);
  acc[6] += __uint_as_float(v.w << 16);
  acc[7] += __uint_as_float(v.w & 0xffff0000u);
}

// Per-block LDS histogram (uint8 packed 4/word). blocks [0,G): dst, [G,2G): src.
__global__ __launch_bounds__(256) void k_hist(const int* __restrict__ src,
                                              const int* __restrict__ dst,
                                              uint* __restrict__ dstH,
                                              uint* __restrict__ srcH) {
  __shared__ uint h[WPN];  // 50 KB
  int b = blockIdx.x;
  bool isDst = b < G;
  int cb = isDst ? b : b - G;
  const int* idx = isDst ? dst : src;
  uint* out = (isDst ? dstH : srcH) + (size_t)cb * WPN;
  for (int w = threadIdx.x; w < WPN; w += 256) h[w] = 0;
  __syncthreads();
  int base = cb * CHE;
  for (int k = threadIdx.x; k < CHE; k += 256) {
    int d = idx[base + k];
    atomicAdd(&h[d >> 2], 1u << ((d & 3) * 8));
  }
  __syncthreads();
  for (int w = threadIdx.x; w < WPN; w += 256) out[w] = h[w];
}

// Column-reduce per-block histograms. dst side: converts dstH in place to
// exclusive per-block byte-prefixes, emits degi/inorm AND per-256-node block
// sums (bsum) -- k_scan1 folded in. src side: onorm only.
__global__ __launch_bounds__(256) void k_reduce(uint* __restrict__ dstH,
                                                const uint* __restrict__ srcH,
                                                int* __restrict__ degi,
                                                float* __restrict__ inorm,
                                                float* __restrict__ onorm,
                                                int* __restrict__ bsum) {
  __shared__ int sh[256];
  int b = blockIdx.x;
  bool isDst = b < 49;
  int cb = isDst ? b : b - 49;
  int col = cb * 256 + threadIdx.x;
  bool valid = col < WPN;
  if (isDst) {
    int degsum = 0;
    if (valid) {
      uint run = 0;
      for (int k = 0; k < G; k++) {
        size_t p = (size_t)k * WPN + col;
        uint v = dstH[p];
        dstH[p] = run;   // exclusive prefix (packed bytes)
        run += v;
      }
      int n0 = col * 4;
      int c0 = run & 255, c1 = (run >> 8) & 255, c2 = (run >> 16) & 255, c3 = (run >> 24) & 255;
      degsum = c0 + c1 + c2 + c3;
      *(int4*)(degi + n0) = make_int4(c0, c1, c2, c3);
      float4 nv;
      nv.x = rsqrtf((float)(c0 > 1 ? c0 : 1));
      nv.y = rsqrtf((float)(c1 > 1 ? c1 : 1));
      nv.z = rsqrtf((float)(c2 > 1 ? c2 : 1));
      nv.w = rsqrtf((float)(c3 > 1 ? c3 : 1));
      *(float4*)(inorm + n0) = nv;
    }
    // per-group (64 threads = 256 nodes) reduction -> bsum
    sh[threadIdx.x] = degsum;
    __syncthreads();
    for (int o = 32; o > 0; o >>= 1) {
      if ((threadIdx.x & 63) < o) sh[threadIdx.x] += sh[threadIdx.x + o];
      __syncthreads();
    }
    if ((threadIdx.x & 63) == 0) bsum[b * 4 + (threadIdx.x >> 6)] = sh[threadIdx.x];
  } else if (valid) {
    uint run = 0;
    for (int k = 0; k < G; k++) run += srcH[(size_t)k * WPN + col];
    int n0 = col * 4;
    int c0 = run & 255, c1 = (run >> 8) & 255, c2 = (run >> 16) & 255, c3 = (run >> 24) & 255;
    float4 nv;
    nv.x = rsqrtf((float)(c0 > 1 ? c0 : 1));
    nv.y = rsqrtf((float)(c1 > 1 ? c1 : 1));
    nv.z = rsqrtf((float)(c2 > 1 ? c2 : 1));
    nv.w = rsqrtf((float)(c3 > 1 ? c3 : 1));
    *(float4*)(onorm + n0) = nv;
  }
}

// Exclusive scan of degi -> off; block offset computed in-block from bsum
// (k_scan2 folded in).
__global__ __launch_bounds__(256) void k_scan3(const int* __restrict__ degi,
                                               const int* __restrict__ bsum,
                                               int* __restrict__ off) {
  __shared__ int sh[256];
  __shared__ int sboff;
  int t = threadIdx.x;
  int lim = blockIdx.x < SCB ? blockIdx.x : SCB;
  sh[t] = (t < lim) ? bsum[t] : 0;
  __syncthreads();
  for (int o = 128; o > 0; o >>= 1) {
    if (t < o) sh[t] += sh[t + o];
    __syncthreads();
  }
  if (t == 0) sboff = sh[0];
  __syncthreads();
  int n = blockIdx.x * 256 + t;
  int v = (n < NN) ? degi[n] : 0;
  sh[t] = v;
  __syncthreads();
  for (int o = 1; o < 256; o <<= 1) {
    int u = (t >= o) ? sh[t - o] : 0;
    __syncthreads();
    sh[t] += u;
    __syncthreads();
  }
  if (n < NN) off[n] = sboff + sh[t] - v;
}

// CSR build with NO global atomics: pos = off[d] + byte-prefix(block) + LDS rank.
__global__ __launch_bounds__(512) void k_csr2(const int* __restrict__ src,
                                              const int* __restrict__ dst,
                                              const int* __restrict__ off,
                                              const uint* __restrict__ dstH,
                                              ushort* __restrict__ csr) {
  __shared__ uint cur[WPN];  // 50 KB byte cursors
  int b = blockIdx.x;
  for (int w = threadIdx.x; w < WPN; w += 512) cur[w] = 0;
  __syncthreads();
  const uint* bb = dstH + (size_t)b * WPN;
  int base = b * CHE;
  for (int k = threadIdx.x; k < CHE; k += 512) {
    int e = base + k;
    int d = dst[e];
    int sh = (d & 3) * 8;
    uint old = atomicAdd(&cur[d >> 2], 1u << sh);
    int rank = (old >> sh) & 255;
    int pre = (bb[d >> 2] >> sh) & 255;
    csr[off[d] + pre + rank] = (ushort)src[e];
  }
}

// H (bf16, node-major [n][128]) = (x @ W1) * onorm.
// Reads coalesced (lanes = consecutive n); writes staged via LDS so the
// global store is one contiguous 32 KB block per workgroup.
// Block 0 also zeroes the 5 contiguous accumulator vectors.
__global__ __launch_bounds__(128) void k_gemm1(const float* __restrict__ x,
                                               const float* __restrict__ W1,
                                               const float* __restrict__ onorm,
                                               ushort* __restrict__ Hb,
                                               float* __restrict__ zeroRegion) {
  __shared__ float w[IND * DD];
  __shared__ uint hb[GNB * 66];  // 66-word padded rows: 2-way-max bank aliasing
  int tid = threadIdx.x;
  if (blockIdx.x == 0) {
    for (int i = tid; i < 5 * NC; i += 128) zeroRegion[i] = 0.f;
  }
  for (int i = tid; i < IND * DD; i += 128) w[i] = W1[i];
  __syncthreads();
  int n0 = blockIdx.x * GNB;
  int n = n0 + tid;
  if (tid < GNB) {
    float on = onorm[n];
    for (int b = 0; b < BB; b++) {
      const float* xb = x + (size_t)b * IND * NN + n;
      float acc[DD];
#pragma unroll
      for (int d = 0; d < DD; d++) acc[d] = 0.f;
      for (int i = 0; i < IND; i++) {
        float v = xb[(size_t)i * NN];
#pragma unroll
        for (int d = 0; d < DD; d++) acc[d] = fmaf(v, w[i * DD + d], acc[d]);
      }
#pragma unroll
      for (int k = 0; k < 8; k++)
        hb[tid * 66 + b * 8 + k] = pack2bf(acc[2 * k] * on, acc[2 * k + 1] * on);
    }
  }
  __syncthreads();
  uint4* outp = (uint4*)((uint*)Hb + (size_t)n0 * 64);
  for (int g4 = tid; g4 < GNB * 16; g4 += 128) {
    int nn = g4 >> 4, ww = (g4 & 15) * 4;
    const uint* p = &hb[nn * 66 + ww];
    outp[g4] = make_uint4(p[0], p[1], p[2], p[3]);
  }
}

// AGG[n][0:128] (fp32) = sum over in-edges of Hb[src][0:128] (bf16).
// 4-deep unrolled edge loop (ILP). Also emits per-block BN-stat partials
// (psum/psq) via LDS reduction -- k_stats' AGG re-read eliminated.
__global__ __launch_bounds__(256) void k_gather(const int* __restrict__ off,
                                                const int* __restrict__ degi,
                                                const ushort* __restrict__ csr,
                                                const ushort* __restrict__ Hb,
                                                const float* __restrict__ inorm,
                                                float* __restrict__ AGG,
                                                float* __restrict__ psum,
                                                float* __restrict__ psq) {
  __shared__ float shs[2048], shq[2048];
  int tid = threadIdx.x;
  int gid = blockIdx.x * 256 + tid;
  int n = gid >> 4;
  int q = (tid & 15) * 8;  // 8 bf16 columns per lane, 16 lanes per node
  int o = off[n], dg = degi[n];
  const ushort* hq = Hb + q;
  float acc[8];
#pragma unroll
  for (int k = 0; k < 8; k++) acc[k] = 0.f;
  int j = 0;
  for (; j + 4 <= dg; j += 4) {
    int s0 = csr[o + j], s1 = csr[o + j + 1], s2 = csr[o + j + 2], s3 = csr[o + j + 3];
    uint4 v0 = *(const uint4*)(hq + (size_t)s0 * NC);
    uint4 v1 = *(const uint4*)(hq + (size_t)s1 * NC);
    uint4 v2 = *(const uint4*)(hq + (size_t)s2 * NC);
    uint4 v3 = *(const uint4*)(hq + (size_t)s3 * NC);
    add8(acc, v0);
    add8(acc, v1);
    add8(acc, v2);
    add8(acc, v3);
  }
  for (; j < dg; j++) {
    int s = csr[o + j];
    uint4 v = *(const uint4*)(hq + (size_t)s * NC);
    add8(acc, v);
  }
  float* op = AGG + (size_t)n * NC + q;
  *(float4*)(op) = make_float4(acc[0], acc[1], acc[2], acc[3]);
  *(float4*)(op + 4) = make_float4(acc[4], acc[5], acc[6], acc[7]);
  // BN-stat partials: a = acc*inorm; reduce 16 node-slots per column.
  float inn = inorm[n];
#pragma unroll
  for (int k = 0; k < 8; k++) {
    float a = acc[k] * inn;
    shs[tid * 8 + k] = a;       // == [slot=tid>>4][col=(tid&15)*8+k]
    shq[tid * 8 + k] = a * a;
  }
  __syncthreads();
  if (tid < 128) {
    float s = 0.f, qq = 0.f;
#pragma unroll
    for (int slot = 0; slot < 16; slot++) {
      s += shs[slot * 128 + tid];
      qq += shq[slot * 128 + tid];
    }
    psum[blockIdx.x * 128 + tid] = s;
    psq[blockIdx.x * 128 + tid] = qq;
  }
}

// Reduce per-block partials (NGB x 128) -> sum / sumsq.
__global__ __launch_bounds__(256) void k_statsr(const float* __restrict__ psum,
                                                const float* __restrict__ psq,
                                                float* __restrict__ sum,
                                                float* __restrict__ sumsq) {
  __shared__ float sh[256];
  int tid = threadIdx.x;
  int c = tid & 127, h = tid >> 7;
  float s = 0.f, q = 0.f;
  for (int i = blockIdx.x * 2 + h; i < NGB; i += 128) {
    s += psum[i * 128 + c];
    q += psq[i * 128 + c];
  }
  sh[tid] = s;
  __syncthreads();
  if (h == 0) unsafeAtomicAdd(&sum[c], s + sh[tid + 128]);
  __syncthreads();
  sh[tid] = q;
  __syncthreads();
  if (h == 0) unsafeAtomicAdd(&sumsq[c], q + sh[tid + 128]);
}

// Hb = bf16((relu(bn1(AGG*inorm)) @ W2) * onorm); BN fold computed in-block.
__global__ void k_applyg2(const float* __restrict__ AGG, const float* __restrict__ inorm,
                          const float* __restrict__ onorm, const float* __restrict__ sum,
                          const float* __restrict__ sumsq, const float* __restrict__ gamma,
                          const float* __restrict__ beta, const float* __restrict__ W2,
                          ushort* __restrict__ Hb) {
  __shared__ float w[DD * DD];
  __shared__ float ssc[NC], stc[NC];
  int tid = threadIdx.x;
  if (tid < DD * DD) w[tid] = W2[tid];
  if (tid < NC) {
    float mu = sum[tid] * (1.0f / NN);
    float var = fmaxf(sumsq[tid] * (1.0f / NN) - mu * mu, 0.f);
    int d = tid & (DD - 1);
    float s = gamma[d] * rsqrtf(var + EPSBN);
    ssc[tid] = s;
    stc[tid] = beta[d] - mu * s;
  }
  __syncthreads();
  int gid = blockIdx.x * 256 + tid;  // gid = n*8 + b
  if (gid >= BB * NN) return;
  int n = gid >> 3, b = gid & 7;
  const float4* ap = (const float4*)(AGG + (size_t)gid * DD);
  float inn = inorm[n];
  float z[DD];
  float4 v0 = ap[0], v1 = ap[1], v2 = ap[2], v3 = ap[3];
  z[0] = v0.x; z[1] = v0.y; z[2] = v0.z; z[3] = v0.w;
  z[4] = v1.x; z[5] = v1.y; z[6] = v1.z; z[7] = v1.w;
  z[8] = v2.x; z[9] = v2.y; z[10] = v2.z; z[11] = v2.w;
  z[12] = v3.x; z[13] = v3.y; z[14] = v3.z; z[15] = v3.w;
#pragma unroll
  for (int d = 0; d < DD; d++) {
    int c = b * DD + d;
    z[d] = fmaxf(0.f, fmaf(z[d] * inn, ssc[c], stc[c]));
  }
  float on = onorm[n];
  float o[DD];
#pragma unroll
  for (int d2 = 0; d2 < DD; d2++) {
    float acc = 0.f;
#pragma unroll
    for (int d = 0; d < DD; d++) acc = fmaf(z[d], w[d * DD + d2], acc);
    o[d2] = acc * on;
  }
  uint p[8];
#pragma unroll
  for (int k = 0; k < 8; k++) p[k] = pack2bf(o[2 * k], o[2 * k + 1]);
  uint* op = (uint*)(Hb + (size_t)gid * DD);
  *(uint4*)(op) = make_uint4(p[0], p[1], p[2], p[3]);
  *(uint4*)(op + 4) = make_uint4(p[4], p[5], p[6], p[7]);
}

// hgsum[c] = sum over n of relu(bn2(AGG*inorm)); BN fold computed in-block.
__global__ void k_final(const float* __restrict__ AGG, const float* __restrict__ inorm,
                        const float* __restrict__ sum, const float* __restrict__ sumsq,
                        const float* __restrict__ gamma, const float* __restrict__ beta,
                        float* __restrict__ hgsum) {
  __shared__ float sh[256];
  __shared__ float ssc[NC], stc[NC];
  int tid = threadIdx.x;
  if (tid < NC) {
    float mu = sum[tid] * (1.0f / NN);
    float var = fmaxf(sumsq[tid] * (1.0f / NN) - mu * mu, 0.f);
    int d = tid & (DD - 1);
    float s = gamma[d] * rsqrtf(var + EPSBN);
    ssc[tid] = s;
    stc[tid] = beta[d] - mu * s;
  }
  __syncthreads();
  int c = tid & (NC - 1);
  int r = tid >> 7;
  float scc = ssc[c], tcc = stc[c];
  float s = 0.f;
  for (int n = blockIdx.x * 2 + r; n < NN; n += gridDim.x * 2) {
    float a = AGG[(size_t)n * NC + c] * inorm[n];
    s += fmaxf(0.f, fmaf(a, scc, tcc));
  }
  sh[tid] = s;
  __syncthreads();
  if (r == 0) unsafeAtomicAdd(&hgsum[c], s + sh[tid + 128]);
}

// final batch-BN over hg[8][16] -> out
__global__ void k_out(const float* __restrict__ hgsum, const float* __restrict__ g,
                      const float* __restrict__ bt, float* __restrict__ out) {
  __shared__ float sh[NC];
  int c = threadIdx.x;
  float hg = hgsum[c] * (1.0f / NN);
  sh[c] = hg;
  __syncthreads();
  int d = c & (DD - 1);
  float mu = 0.f;
#pragma unroll
  for (int b = 0; b < BB; b++) mu += sh[b * DD + d];
  mu *= (1.0f / BB);
  float var = 0.f;
#pragma unroll
  for (int b = 0; b < BB; b++) { float t = sh[b * DD + d] - mu; var = fmaf(t, t, var); }
  var *= (1.0f / BB);
  out[c] = fmaf((hg - mu) * rsqrtf(var + EPSBN), g[d], bt[d]);
}

extern "C" void kernel_launch(void* const* d_in, const int* in_sizes, int n_in,
                              void* d_out, int out_size, void* d_ws, size_t ws_size,
                              hipStream_t stream) {
  const float* x   = (const float*)d_in[0];
  const float* W1  = (const float*)d_in[1];
  // d_in[2] = b1: cancels inside BN1 (affine) -- unused
  const float* g1g = (const float*)d_in[3];
  const float* g1b = (const float*)d_in[4];
  const float* W2  = (const float*)d_in[5];
  // d_in[6] = b2: cancels inside BN2 -- unused
  const float* g2g = (const float*)d_in[7];
  const float* g2b = (const float*)d_in[8];
  const float* n1g = (const float*)d_in[9];
  const float* n1b = (const float*)d_in[10];
  const int* src   = (const int*)d_in[11];
  const int* dst   = (const int*)d_in[12];
  float* out = (float*)d_out;

  char* w = (char*)d_ws;
  float* AGG   = (float*)w; w += (size_t)NN * NC * 4;
  ushort* Hb   = (ushort*)w; w += (size_t)NN * NC * 2;
  int* degi    = (int*)w;   w += (size_t)NN * 4;
  int* off     = (int*)w;   w += (size_t)NN * 4;
  ushort* csr  = (ushort*)w; w += (size_t)NE * 2;
  float* onorm = (float*)w; w += (size_t)NN * 4;
  float* inorm = (float*)w; w += (size_t)NN * 4;
  int* bsum    = (int*)w;   w += (size_t)SCB * 4;
  float* psum  = (float*)w; w += (size_t)NGB * NC * 4;
  float* psq   = (float*)w; w += (size_t)NGB * NC * 4;
  // 5 contiguous accumulator vectors (zeroed by k_gemm1 block 0):
  float* sum1  = (float*)w; w += NC * 4;
  float* sq1   = (float*)w; w += NC * 4;
  float* sum2  = (float*)w; w += NC * 4;
  float* sq2   = (float*)w; w += NC * 4;
  float* hgsum = (float*)w; w += NC * 4;

  // Histogram regions overlay AGG (12.8 MB < 25.6 MB); AGG is first written by
  // k_gather, which runs after k_csr2 has consumed the histograms.
  uint* dstH = (uint*)AGG;
  uint* srcH = dstH + (size_t)G * WPN;

  k_hist<<<2 * G, 256, 0, stream>>>(src, dst, dstH, srcH);
  k_reduce<<<98, 256, 0, stream>>>(dstH, srcH, degi, inorm, onorm, bsum);
  k_scan3<<<SCB, 256, 0, stream>>>(degi, bsum, off);
  k_csr2<<<G, 512, 0, stream>>>(src, dst, off, dstH, csr);
  k_gemm1<<<NN / GNB, 128, 0, stream>>>(x, W1, onorm, Hb, sum1);
  k_gather<<<NGB, 256, 0, stream>>>(off, degi, csr, Hb, inorm, AGG, psum, psq);
  k_statsr<<<64, 256, 0, stream>>>(psum, psq, sum1, sq1);
  k_applyg2<<<(BB * NN + 255) / 256, 256, 0, stream>>>(AGG, inorm, onorm, sum1, sq1,
                                                       g1g, g1b, W2, Hb);
  k_gather<<<NGB, 256, 0, stream>>>(off, degi, csr, Hb, inorm, AGG, psum, psq);
  k_statsr<<<64, 256, 0, stream>>>(psum, psq, sum2, sq2);
  k_final<<<512, 256, 0, stream>>>(AGG, inorm, sum2, sq2, g2g, g2b, hgsum);
  k_out<<<1, NC, 0, stream>>>(hgsum, n1g, n1b, out);
}

// Round 8
// 195.667 us; speedup vs baseline: 1.3527x; 1.3527x over previous
//
#include <hip/hip_runtime.h>

#define NN 50000
#define NE 800000
#define IND 32
#define DD 16
#define BB 8
#define NC 128   // BB*DD
#define EPSBN 1e-5f
#define SCB ((NN + 255) / 256)   // 196 scan blocks
#define G 128                    // histogram blocks per direction
#define CHE (NE / G)             // 6250 edges per hist block
#define WPN (NN / 4)             // 12500 packed words (4 uint8 counters each)
#define GB 32                    // nodes per gemm1 block
#define NGB 3125                 // gather blocks (16 nodes each, exact)

typedef unsigned int uint;
typedef unsigned short ushort;

__device__ __forceinline__ ushort f2bf(float f) {
  uint u = __float_as_uint(f);
  return (ushort)((u + 0x7fffu + ((u >> 16) & 1u)) >> 16);  // RNE
}
__device__ __forceinline__ uint pack2bf(float lo, float hi) {
  return (uint)f2bf(lo) | ((uint)f2bf(hi) << 16);
}
__device__ __forceinline__ void add8(float* acc, uint4 v) {
  acc[0] += __uint_as_float(v.x << 16);
  acc[1] += __uint_as_float(v.x & 0xffff0000u);
  acc[2] += __uint_as_float(v.y << 16);
  acc[3] += __uint_as_float(v.y & 0xffff0000u);
  acc[4] += __uint_as_float(v.z << 16);
  acc[5] += __uint_as_float(v.z & 0xffff0000u);
  acc[6] += __uint_as_float(v.w << 16);
  acc[7] += __uint_as_float(v.w & 0xffff0000u);
}

// Per-block LDS histogram (uint8 packed 4/word). blocks [0,G): dst, [G,2G): src.
__global__ __launch_bounds__(256) void k_hist(const int* __restrict__ src,
                                              const int* __restrict__ dst,
                                              uint* __restrict__ dstH,
                                              uint* __restrict__ srcH) {
  __shared__ uint h[WPN];  // 50 KB
  int b = blockIdx.x;
  bool isDst = b < G;
  int cb = isDst ? b : b - G;
  const int* idx = isDst ? dst : src;
  uint* out = (isDst ? dstH : srcH) + (size_t)cb * WPN;
  for (int w = threadIdx.x; w < WPN; w += 256) h[w] = 0;
  __syncthreads();
  int base = cb * CHE;
  for (int k = threadIdx.x; k < CHE; k += 256) {
    int d = idx[base + k];
    atomicAdd(&h[d >> 2], 1u << ((d & 3) * 8));
  }
  __syncthreads();
  for (int w = threadIdx.x; w < WPN; w += 256) out[w] = h[w];
}

// Column-reduce per-block histograms. dst side: converts dstH in place to
// exclusive per-block byte-prefixes, emits degi/inorm AND per-256-node block
// sums (bsum) -- k_scan1 folded in. src side: onorm only.
__global__ __launch_bounds__(256) void k_reduce(uint* __restrict__ dstH,
                                                const uint* __restrict__ srcH,
                                                int* __restrict__ degi,
                                                float* __restrict__ inorm,
                                                float* __restrict__ onorm,
                                                int* __restrict__ bsum) {
  __shared__ int sh[256];
  int b = blockIdx.x;
  bool isDst = b < 49;
  int cb = isDst ? b : b - 49;
  int col = cb * 256 + threadIdx.x;
  bool valid = col < WPN;
  if (isDst) {
    int degsum = 0;
    if (valid) {
      uint run = 0;
      for (int k = 0; k < G; k++) {
        size_t p = (size_t)k * WPN + col;
        uint v = dstH[p];
        dstH[p] = run;   // exclusive prefix (packed bytes)
        run += v;
      }
      int n0 = col * 4;
      int c0 = run & 255, c1 = (run >> 8) & 255, c2 = (run >> 16) & 255, c3 = (run >> 24) & 255;
      degsum = c0 + c1 + c2 + c3;
      *(int4*)(degi + n0) = make_int4(c0, c1, c2, c3);
      float4 nv;
      nv.x = rsqrtf((float)(c0 > 1 ? c0 : 1));
      nv.y = rsqrtf((float)(c1 > 1 ? c1 : 1));
      nv.z = rsqrtf((float)(c2 > 1 ? c2 : 1));
      nv.w = rsqrtf((float)(c3 > 1 ? c3 : 1));
      *(float4*)(inorm + n0) = nv;
    }
    // per-group (64 threads = 256 nodes) reduction -> bsum
    sh[threadIdx.x] = degsum;
    __syncthreads();
    for (int o = 32; o > 0; o >>= 1) {
      if ((threadIdx.x & 63) < o) sh[threadIdx.x] += sh[threadIdx.x + o];
      __syncthreads();
    }
    if ((threadIdx.x & 63) == 0) bsum[b * 4 + (threadIdx.x >> 6)] = sh[threadIdx.x];
  } else if (valid) {
    uint run = 0;
    for (int k = 0; k < G; k++) run += srcH[(size_t)k * WPN + col];
    int n0 = col * 4;
    int c0 = run & 255, c1 = (run >> 8) & 255, c2 = (run >> 16) & 255, c3 = (run >> 24) & 255;
    float4 nv;
    nv.x = rsqrtf((float)(c0 > 1 ? c0 : 1));
    nv.y = rsqrtf((float)(c1 > 1 ? c1 : 1));
    nv.z = rsqrtf((float)(c2 > 1 ? c2 : 1));
    nv.w = rsqrtf((float)(c3 > 1 ? c3 : 1));
    *(float4*)(onorm + n0) = nv;
  }
}

// Exclusive scan of degi -> off; block offset computed in-block from bsum
// (k_scan2 folded in).
__global__ __launch_bounds__(256) void k_scan3(const int* __restrict__ degi,
                                               const int* __restrict__ bsum,
                                               int* __restrict__ off) {
  __shared__ int sh[256];
  __shared__ int sboff;
  int t = threadIdx.x;
  int lim = blockIdx.x < SCB ? blockIdx.x : SCB;
  sh[t] = (t < lim) ? bsum[t] : 0;
  __syncthreads();
  for (int o = 128; o > 0; o >>= 1) {
    if (t < o) sh[t] += sh[t + o];
    __syncthreads();
  }
  if (t == 0) sboff = sh[0];
  __syncthreads();
  int n = blockIdx.x * 256 + t;
  int v = (n < NN) ? degi[n] : 0;
  sh[t] = v;
  __syncthreads();
  for (int o = 1; o < 256; o <<= 1) {
    int u = (t >= o) ? sh[t - o] : 0;
    __syncthreads();
    sh[t] += u;
    __syncthreads();
  }
  if (n < NN) off[n] = sboff + sh[t] - v;
}

// CSR build with NO global atomics: pos = off[d] + byte-prefix(block) + LDS rank.
__global__ __launch_bounds__(512) void k_csr2(const int* __restrict__ src,
                                              const int* __restrict__ dst,
                                              const int* __restrict__ off,
                                              const uint* __restrict__ dstH,
                                              ushort* __restrict__ csr) {
  __shared__ uint cur[WPN];  // 50 KB byte cursors
  int b = blockIdx.x;
  for (int w = threadIdx.x; w < WPN; w += 512) cur[w] = 0;
  __syncthreads();
  const uint* bb = dstH + (size_t)b * WPN;
  int base = b * CHE;
  for (int k = threadIdx.x; k < CHE; k += 512) {
    int e = base + k;
    int d = dst[e];
    int sh = (d & 3) * 8;
    uint old = atomicAdd(&cur[d >> 2], 1u << sh);
    int rank = (old >> sh) & 255;
    int pre = (bb[d >> 2] >> sh) & 255;
    csr[off[d] + pre + rank] = (ushort)src[e];
  }
}

// H (bf16, node-major [n][128]) = (x @ W1) * onorm.
// Thread (b, n_local): tid = b*32 + n_local. Reads: wave = 2 b's x 32
// consecutive n -> 2x128B segments. Writes: 8 KB LDS tile (padded rows),
// then one contiguous uint4 stream per block.
__global__ __launch_bounds__(256) void k_gemm1(const float* __restrict__ x,
                                               const float* __restrict__ W1,
                                               const float* __restrict__ onorm,
                                               ushort* __restrict__ Hb,
                                               float* __restrict__ zeroRegion) {
  __shared__ float w[IND * DD];
  __shared__ uint hb[GB * 65];  // 65-word padded rows
  int tid = threadIdx.x;
  if (blockIdx.x == 0) {
    for (int i = tid; i < 5 * NC; i += 256) zeroRegion[i] = 0.f;
  }
  for (int i = tid; i < IND * DD; i += 256) w[i] = W1[i];
  __syncthreads();
  int b = tid >> 5;        // sample 0..7
  int nl = tid & 31;       // node slot 0..31
  int n0 = blockIdx.x * GB;
  int n = n0 + nl;
  if (n < NN) {
    const float* xb = x + (size_t)b * IND * NN + n;
    float acc[DD];
#pragma unroll
    for (int d = 0; d < DD; d++) acc[d] = 0.f;
    for (int i = 0; i < IND; i++) {
      float v = xb[(size_t)i * NN];
#pragma unroll
      for (int d = 0; d < DD; d++) acc[d] = fmaf(v, w[i * DD + d], acc[d]);
    }
    float on = onorm[n];
#pragma unroll
    for (int k = 0; k < 8; k++)
      hb[nl * 65 + b * 8 + k] = pack2bf(acc[2 * k] * on, acc[2 * k + 1] * on);
  }
  __syncthreads();
  int nblk = (NN - n0 < GB) ? NN - n0 : GB;
  uint4* outp = (uint4*)((uint*)Hb + (size_t)n0 * 64);
  for (int g4 = tid; g4 < nblk * 16; g4 += 256) {
    int nn = g4 >> 4, ww = (g4 & 15) * 4;
    const uint* p = &hb[nn * 65 + ww];
    outp[g4] = make_uint4(p[0], p[1], p[2], p[3]);
  }
}

// AGG[n][0:128] (fp32) = sum over in-edges of Hb[src][0:128] (bf16).
// 4-deep unrolled edge loop (ILP). Also emits per-block BN-stat partials
// (psum/psq) via LDS reduction -- k_stats' AGG re-read eliminated.
__global__ __launch_bounds__(256) void k_gather(const int* __restrict__ off,
                                                const int* __restrict__ degi,
                                                const ushort* __restrict__ csr,
                                                const ushort* __restrict__ Hb,
                                                const float* __restrict__ inorm,
                                                float* __restrict__ AGG,
                                                float* __restrict__ psum,
                                                float* __restrict__ psq) {
  __shared__ float shs[2048], shq[2048];
  int tid = threadIdx.x;
  int gid = blockIdx.x * 256 + tid;
  int n = gid >> 4;
  int q = (tid & 15) * 8;  // 8 bf16 columns per lane, 16 lanes per node
  int o = off[n], dg = degi[n];
  const ushort* hq = Hb + q;
  float acc[8];
#pragma unroll
  for (int k = 0; k < 8; k++) acc[k] = 0.f;
  int j = 0;
  for (; j + 4 <= dg; j += 4) {
    int s0 = csr[o + j], s1 = csr[o + j + 1], s2 = csr[o + j + 2], s3 = csr[o + j + 3];
    uint4 v0 = *(const uint4*)(hq + (size_t)s0 * NC);
    uint4 v1 = *(const uint4*)(hq + (size_t)s1 * NC);
    uint4 v2 = *(const uint4*)(hq + (size_t)s2 * NC);
    uint4 v3 = *(const uint4*)(hq + (size_t)s3 * NC);
    add8(acc, v0);
    add8(acc, v1);
    add8(acc, v2);
    add8(acc, v3);
  }
  for (; j < dg; j++) {
    int s = csr[o + j];
    uint4 v = *(const uint4*)(hq + (size_t)s * NC);
    add8(acc, v);
  }
  float* op = AGG + (size_t)n * NC + q;
  *(float4*)(op) = make_float4(acc[0], acc[1], acc[2], acc[3]);
  *(float4*)(op + 4) = make_float4(acc[4], acc[5], acc[6], acc[7]);
  // BN-stat partials: a = acc*inorm; reduce 16 node-slots per column.
  float inn = inorm[n];
#pragma unroll
  for (int k = 0; k < 8; k++) {
    float a = acc[k] * inn;
    shs[tid * 8 + k] = a;       // == [slot=tid>>4][col=(tid&15)*8+k]
    shq[tid * 8 + k] = a * a;
  }
  __syncthreads();
  if (tid < 128) {
    float s = 0.f, qq = 0.f;
#pragma unroll
    for (int slot = 0; slot < 16; slot++) {
      s += shs[slot * 128 + tid];
      qq += shq[slot * 128 + tid];
    }
    psum[blockIdx.x * 128 + tid] = s;
    psq[blockIdx.x * 128 + tid] = qq;
  }
}

// Reduce per-block partials (NGB x 128) -> sum / sumsq.
__global__ __launch_bounds__(256) void k_statsr(const float* __restrict__ psum,
                                                const float* __restrict__ psq,
                                                float* __restrict__ sum,
                                                float* __restrict__ sumsq) {
  __shared__ float sh[256];
  int tid = threadIdx.x;
  int c = tid & 127, h = tid >> 7;
  float s = 0.f, q = 0.f;
  for (int i = blockIdx.x * 2 + h; i < NGB; i += 128) {
    s += psum[i * 128 + c];
    q += psq[i * 128 + c];
  }
  sh[tid] = s;
  __syncthreads();
  if (h == 0) unsafeAtomicAdd(&sum[c], s + sh[tid + 128]);
  __syncthreads();
  sh[tid] = q;
  __syncthreads();
  if (h == 0) unsafeAtomicAdd(&sumsq[c], q + sh[tid + 128]);
}

// Hb = bf16((relu(bn1(AGG*inorm)) @ W2) * onorm); BN fold computed in-block.
__global__ void k_applyg2(const float* __restrict__ AGG, const float* __restrict__ inorm,
                          const float* __restrict__ onorm, const float* __restrict__ sum,
                          const float* __restrict__ sumsq, const float* __restrict__ gamma,
                          const float* __restrict__ beta, const float* __restrict__ W2,
                          ushort* __restrict__ Hb) {
  __shared__ float w[DD * DD];
  __shared__ float ssc[NC], stc[NC];
  int tid = threadIdx.x;
  if (tid < DD * DD) w[tid] = W2[tid];
  if (tid < NC) {
    float mu = sum[tid] * (1.0f / NN);
    float var = fmaxf(sumsq[tid] * (1.0f / NN) - mu * mu, 0.f);
    int d = tid & (DD - 1);
    float s = gamma[d] * rsqrtf(var + EPSBN);
    ssc[tid] = s;
    stc[tid] = beta[d] - mu * s;
  }
  __syncthreads();
  int gid = blockIdx.x * 256 + tid;  // gid = n*8 + b
  if (gid >= BB * NN) return;
  int n = gid >> 3, b = gid & 7;
  const float4* ap = (const float4*)(AGG + (size_t)gid * DD);
  float inn = inorm[n];
  float z[DD];
  float4 v0 = ap[0], v1 = ap[1], v2 = ap[2], v3 = ap[3];
  z[0] = v0.x; z[1] = v0.y; z[2] = v0.z; z[3] = v0.w;
  z[4] = v1.x; z[5] = v1.y; z[6] = v1.z; z[7] = v1.w;
  z[8] = v2.x; z[9] = v2.y; z[10] = v2.z; z[11] = v2.w;
  z[12] = v3.x; z[13] = v3.y; z[14] = v3.z; z[15] = v3.w;
#pragma unroll
  for (int d = 0; d < DD; d++) {
    int c = b * DD + d;
    z[d] = fmaxf(0.f, fmaf(z[d] * inn, ssc[c], stc[c]));
  }
  float on = onorm[n];
  float o[DD];
#pragma unroll
  for (int d2 = 0; d2 < DD; d2++) {
    float acc = 0.f;
#pragma unroll
    for (int d = 0; d < DD; d++) acc = fmaf(z[d], w[d * DD + d2], acc);
    o[d2] = acc * on;
  }
  uint p[8];
#pragma unroll
  for (int k = 0; k < 8; k++) p[k] = pack2bf(o[2 * k], o[2 * k + 1]);
  uint* op = (uint*)(Hb + (size_t)gid * DD);
  *(uint4*)(op) = make_uint4(p[0], p[1], p[2], p[3]);
  *(uint4*)(op + 4) = make_uint4(p[4], p[5], p[6], p[7]);
}

// hgsum[c] = sum over n of relu(bn2(AGG*inorm)); BN fold computed in-block.
__global__ void k_final(const float* __restrict__ AGG, const float* __restrict__ inorm,
                        const float* __restrict__ sum, const float* __restrict__ sumsq,
                        const float* __restrict__ gamma, const float* __restrict__ beta,
                        float* __restrict__ hgsum) {
  __shared__ float sh[256];
  __shared__ float ssc[NC], stc[NC];
  int tid = threadIdx.x;
  if (tid < NC) {
    float mu = sum[tid] * (1.0f / NN);
    float var = fmaxf(sumsq[tid] * (1.0f / NN) - mu * mu, 0.f);
    int d = tid & (DD - 1);
    float s = gamma[d] * rsqrtf(var + EPSBN);
    ssc[tid] = s;
    stc[tid] = beta[d] - mu * s;
  }
  __syncthreads();
  int c = tid & (NC - 1);
  int r = tid >> 7;
  float scc = ssc[c], tcc = stc[c];
  float s = 0.f;
  for (int n = blockIdx.x * 2 + r; n < NN; n += gridDim.x * 2) {
    float a = AGG[(size_t)n * NC + c] * inorm[n];
    s += fmaxf(0.f, fmaf(a, scc, tcc));
  }
  sh[tid] = s;
  __syncthreads();
  if (r == 0) unsafeAtomicAdd(&hgsum[c], s + sh[tid + 128]);
}

// final batch-BN over hg[8][16] -> out
__global__ void k_out(const float* __restrict__ hgsum, const float* __restrict__ g,
                      const float* __restrict__ bt, float* __restrict__ out) {
  __shared__ float sh[NC];
  int c = threadIdx.x;
  float hg = hgsum[c] * (1.0f / NN);
  sh[c] = hg;
  __syncthreads();
  int d = c & (DD - 1);
  float mu = 0.f;
#pragma unroll
  for (int b = 0; b < BB; b++) mu += sh[b * DD + d];
  mu *= (1.0f / BB);
  float var = 0.f;
#pragma unroll
  for (int b = 0; b < BB; b++) { float t = sh[b * DD + d] - mu; var = fmaf(t, t, var); }
  var *= (1.0f / BB);
  out[c] = fmaf((hg - mu) * rsqrtf(var + EPSBN), g[d], bt[d]);
}

extern "C" void kernel_launch(void* const* d_in, const int* in_sizes, int n_in,
                              void* d_out, int out_size, void* d_ws, size_t ws_size,
                              hipStream_t stream) {
  const float* x   = (const float*)d_in[0];
  const float* W1  = (const float*)d_in[1];
  // d_in[2] = b1: cancels inside BN1 (affine) -- unused
  const float* g1g = (const float*)d_in[3];
  const float* g1b = (const float*)d_in[4];
  const float* W2  = (const float*)d_in[5];
  // d_in[6] = b2: cancels inside BN2 -- unused
  const float* g2g = (const float*)d_in[7];
  const float* g2b = (const float*)d_in[8];
  const float* n1g = (const float*)d_in[9];
  const float* n1b = (const float*)d_in[10];
  const int* src   = (const int*)d_in[11];
  const int* dst   = (const int*)d_in[12];
  float* out = (float*)d_out;

  char* w = (char*)d_ws;
  float* AGG   = (float*)w; w += (size_t)NN * NC * 4;
  ushort* Hb   = (ushort*)w; w += (size_t)NN * NC * 2;
  int* degi    = (int*)w;   w += (size_t)NN * 4;
  int* off     = (int*)w;   w += (size_t)NN * 4;
  ushort* csr  = (ushort*)w; w += (size_t)NE * 2;
  float* onorm = (float*)w; w += (size_t)NN * 4;
  float* inorm = (float*)w; w += (size_t)NN * 4;
  int* bsum    = (int*)w;   w += (size_t)SCB * 4;
  float* psum  = (float*)w; w += (size_t)NGB * NC * 4;
  float* psq   = (float*)w; w += (size_t)NGB * NC * 4;
  // 5 contiguous accumulator vectors (zeroed by k_gemm1 block 0):
  float* sum1  = (float*)w; w += NC * 4;
  float* sq1   = (float*)w; w += NC * 4;
  float* sum2  = (float*)w; w += NC * 4;
  float* sq2   = (float*)w; w += NC * 4;
  float* hgsum = (float*)w; w += NC * 4;

  // Histogram regions overlay AGG (12.8 MB < 25.6 MB); AGG is first written by
  // k_gather, which runs after k_csr2 has consumed the histograms.
  uint* dstH = (uint*)AGG;
  uint* srcH = dstH + (size_t)G * WPN;

  k_hist<<<2 * G, 256, 0, stream>>>(src, dst, dstH, srcH);
  k_reduce<<<98, 256, 0, stream>>>(dstH, srcH, degi, inorm, onorm, bsum);
  k_scan3<<<SCB, 256, 0, stream>>>(degi, bsum, off);
  k_csr2<<<G, 512, 0, stream>>>(src, dst, off, dstH, csr);
  k_gemm1<<<(NN + GB - 1) / GB, 256, 0, stream>>>(x, W1, onorm, Hb, sum1);
  k_gather<<<NGB, 256, 0, stream>>>(off, degi, csr, Hb, inorm, AGG, psum, psq);
  k_statsr<<<64, 256, 0, stream>>>(psum, psq, sum1, sq1);
  k_applyg2<<<(BB * NN + 255) / 256, 256, 0, stream>>>(AGG, inorm, onorm, sum1, sq1,
                                                       g1g, g1b, W2, Hb);
  k_gather<<<NGB, 256, 0, stream>>>(off, degi, csr, Hb, inorm, AGG, psum, psq);
  k_statsr<<<64, 256, 0, stream>>>(psum, psq, sum2, sq2);
  k_final<<<512, 256, 0, stream>>>(AGG, inorm, sum2, sq2, g2g, g2b, hgsum);
  k_out<<<1, NC, 0, stream>>>(hgsum, n1g, n1b, out);
}